// Round 1
// baseline (423.818 us; speedup 1.0000x reference)
//
#include <hip/hip_runtime.h>
#include <math.h>

// VIN forward on MI355X.
// Sizes: N=128, H=W=64, CH_I=2, CH_H=150, CH_Q=10, N_ACT=8, VInum=36.
//
// Plan:
//  prep_kernel (1 WG): compose r = conv(conv(x,w0)+b0, w_r) into an effective
//    5x5x2 conv W5 + bias terms B[9]/Btot (valid in the interior; border fixed
//    in the main kernel by subtracting the "virtual h" contributions).
//  vin_kernel (128 WGs x 1024 thr): per batch element, everything LDS-resident:
//    stage x -> r (5x5 conv + border fix) -> Rsw precompute (loop-invariant
//    r-part of the shared-weight conv, kept in registers: 4px x 10 actions)
//    -> 1 step w_q -> (K-1) steps w_sw (double-buffered v in LDS, 1 barrier/it)
//    -> final step w_sw2 writes q, gather (S1,S2), dense 10x8, softmax.

#define POOL_F (68 * 68 * 2)   // x staging [68][68][2]; later reused as v[2][66][66]
#define VSTRIDE (66 * 66)

__global__ void prep_kernel(const float* __restrict__ w0,
                            const float* __restrict__ b0,
                            const float* __restrict__ w_r,
                            float* __restrict__ ws) {
    int idx = threadIdx.x;
    if (idx < 50) {
        int e = idx >> 1;          // 0..24
        int ci = idx & 1;
        int ey = e / 5 - 2, ex = e % 5 - 2;
        float s = 0.f;
        for (int dqy = -1; dqy <= 1; ++dqy)
            for (int dqx = -1; dqx <= 1; ++dqx) {
                int dsy = ey - dqy, dsx = ex - dqx;
                if (dsy < -1 || dsy > 1 || dsx < -1 || dsx > 1) continue;
                const float* wr = w_r + ((dqy + 1) * 3 + (dqx + 1)) * 150;
                const float* wp = w0 + (((dsy + 1) * 3 + (dsx + 1)) * 2 + ci) * 150;
                for (int c = 0; c < 150; ++c) s += wr[c] * wp[c];
            }
        ws[idx] = s;               // W5[(ey+2)*5+(ex+2)][ci]
    } else if (idx < 59) {
        int d = idx - 50;          // B[d] = sum_c w_r[d][c] * b0[c]
        float s = 0.f;
        for (int c = 0; c < 150; ++c) s += w_r[d * 150 + c] * b0[c];
        ws[50 + d] = s;
    } else if (idx == 59) {
        float s = 0.f;
        for (int d = 0; d < 9; ++d)
            for (int c = 0; c < 150; ++c) s += w_r[d * 150 + c] * b0[c];
        ws[59] = s;                // Btot
    }
}

__global__ __launch_bounds__(1024)
void vin_kernel(const float* __restrict__ x,
                const int* __restrict__ S1,
                const int* __restrict__ S2,
                const int* __restrict__ VInum,
                const float* __restrict__ w0,
                const float* __restrict__ w_r,
                const float* __restrict__ w_q,
                const float* __restrict__ w_sw,
                const float* __restrict__ w_sw2,
                const float* __restrict__ w_dense,
                const float* __restrict__ ws,
                float* __restrict__ out) {
    const int b = blockIdx.x;
    const int t = threadIdx.x;

    __shared__ float pool[POOL_F];   // phase 1: xs[68][68][2]; phase 2: v[2][66][66]
    __shared__ float rs[66 * 66];    // r with 1-halo of zeros
    __shared__ float qsel[10];

    // ---- zero LDS (halos must be 0) ----
    for (int i = t; i < POOL_F; i += 1024) pool[i] = 0.f;
    for (int i = t; i < 66 * 66; i += 1024) rs[i] = 0.f;
    __syncthreads();

    const int row = t >> 4;          // 0..63, one row per 16 threads
    const int cb  = (t & 15) << 2;   // column base: 0,4,...,60 (4 px per thread)

    // ---- stage x into pool as xs[y+2][x+2][ci] (2-halo of zeros) ----
    {
        const float* xb = x + (size_t)b * 64 * 64 * 2;
        #pragma unroll
        for (int p = 0; p < 4; ++p) {
            int xx = cb + p;
            float2 v2 = *(const float2*)(xb + (row * 64 + xx) * 2);
            pool[((row + 2) * 68 + (xx + 2)) * 2 + 0] = v2.x;
            pool[((row + 2) * 68 + (xx + 2)) * 2 + 1] = v2.y;
        }
    }
    __syncthreads();

    // ---- r interior via composed 5x5 conv ----
    {
        float W5a[25], W5b[25];
        #pragma unroll
        for (int e = 0; e < 25; ++e) { W5a[e] = ws[e * 2]; W5b[e] = ws[e * 2 + 1]; }
        float Btot = ws[59];
        #pragma unroll
        for (int p = 0; p < 4; ++p) {
            int xx = cb + p;
            float acc = Btot;
            #pragma unroll
            for (int ey = 0; ey < 5; ++ey)
                #pragma unroll
                for (int ex = 0; ex < 5; ++ex) {
                    const float* xp = &pool[((row + ey) * 68 + (xx + ex)) * 2];
                    acc += xp[0] * W5a[ey * 5 + ex] + xp[1] * W5b[ey * 5 + ex];
                }
            rs[(row + 1) * 66 + (xx + 1)] = acc;
        }
    }
    __syncthreads();

    // ---- border fix: subtract virtual-h contributions from 260 outside-q ----
    // q positions: rows -1,64 (cols -1..64) and cols -1,64 (rows 0..63).
    // 3 threads per q, 50 channels each.
    if (t < 780) {
        int qi = t / 3, ch = t - qi * 3;
        int qy, qx;
        if (qi < 66)       { qy = -1; qx = qi - 1; }
        else if (qi < 132) { qy = 64; qx = qi - 67; }
        else if (qi < 196) { qx = -1; qy = qi - 132; }
        else               { qx = 64; qy = qi - 196; }
        float sdq[9];
        #pragma unroll
        for (int d = 0; d < 9; ++d) sdq[d] = 0.f;
        int c0 = ch * 50;
        for (int c = c0; c < c0 + 50; ++c) {
            float hc = 0.f;
            #pragma unroll
            for (int ky = 0; ky < 3; ++ky)
                #pragma unroll
                for (int kx = 0; kx < 3; ++kx) {
                    const float* xp = &pool[((qy + ky + 1) * 68 + (qx + kx + 1)) * 2];
                    const float* wp = &w0[((ky * 3 + kx) * 2) * 150 + c];
                    hc += xp[0] * wp[0] + xp[1] * wp[150];
                }
            #pragma unroll
            for (int d = 0; d < 9; ++d) sdq[d] += w_r[d * 150 + c] * hc;
        }
        #pragma unroll
        for (int d = 0; d < 9; ++d) {
            int dy = d / 3 - 1, dx = d % 3 - 1;
            int py = qy - dy, px = qx - dx;
            if (py >= 0 && py < 64 && px >= 0 && px < 64) {
                float corr = sdq[d] + (ch == 0 ? ws[50 + d] : 0.f);
                atomicAdd(&rs[(py + 1) * 66 + (px + 1)], -corr);
            }
        }
    }
    __syncthreads();

    // ---- reuse pool as v[2][66][66]: re-zero (halos!) ----
    for (int i = t; i < 2 * VSTRIDE; i += 1024) pool[i] = 0.f;
    __syncthreads();

    const int K = VInum[0];

    // ---- Rsw precompute (loop-invariant r-part of w_sw conv) + first step (w_q) ----
    float Rsw[4][10];
    {
        float rwin[3][6];
        #pragma unroll
        for (int i = 0; i < 3; ++i)
            #pragma unroll
            for (int j = 0; j < 6; ++j)
                rwin[i][j] = rs[(row + i) * 66 + (cb + j)];
        float vmax[4];
        #pragma unroll
        for (int a = 0; a < 10; ++a) {
            #pragma unroll
            for (int p = 0; p < 4; ++p) {
                float accR = 0.f, accQ = 0.f;
                #pragma unroll
                for (int d = 0; d < 9; ++d) {
                    float rv = rwin[d / 3][p + d % 3];
                    accR += w_sw[d * 20 + a] * rv;   // ci=0 (r channel)
                    accQ += w_q[d * 20 + a] * rv;
                }
                Rsw[p][a] = accR;
                vmax[p] = (a == 0) ? accQ : fmaxf(vmax[p], accQ);
            }
        }
        #pragma unroll
        for (int p = 0; p < 4; ++p)
            pool[0 * VSTRIDE + (row + 1) * 66 + (cb + p + 1)] = vmax[p];
    }
    __syncthreads();

    // ---- K-1 shared-weight VI steps, double-buffered v ----
    int cur = 0;
    for (int it = 0; it < K - 1; ++it) {
        float vwin[3][6];
        #pragma unroll
        for (int i = 0; i < 3; ++i)
            #pragma unroll
            for (int j = 0; j < 6; ++j)
                vwin[i][j] = pool[cur * VSTRIDE + (row + i) * 66 + (cb + j)];
        float vmax[4];
        #pragma unroll
        for (int a = 0; a < 10; ++a) {
            #pragma unroll
            for (int p = 0; p < 4; ++p) {
                float acc = Rsw[p][a];
                #pragma unroll
                for (int d = 0; d < 9; ++d)
                    acc += w_sw[d * 20 + 10 + a] * vwin[d / 3][p + d % 3];
                vmax[p] = (a == 0) ? acc : fmaxf(vmax[p], acc);
            }
        }
        int nxt = cur ^ 1;
        #pragma unroll
        for (int p = 0; p < 4; ++p)
            pool[nxt * VSTRIDE + (row + 1) * 66 + (cb + p + 1)] = vmax[p];
        cur = nxt;
        __syncthreads();
    }

    // ---- final step with w_sw2: q -> global, gather (S1,S2) ----
    const int s1 = S1[b], s2 = S2[b];
    {
        float rwin[3][6], vwin[3][6];
        #pragma unroll
        for (int i = 0; i < 3; ++i)
            #pragma unroll
            for (int j = 0; j < 6; ++j) {
                rwin[i][j] = rs[(row + i) * 66 + (cb + j)];
                vwin[i][j] = pool[cur * VSTRIDE + (row + i) * 66 + (cb + j)];
            }
        float qv[4][10];
        #pragma unroll
        for (int a = 0; a < 10; ++a) {
            #pragma unroll
            for (int p = 0; p < 4; ++p) {
                float acc = 0.f;
                #pragma unroll
                for (int d = 0; d < 9; ++d) {
                    acc += w_sw2[d * 20 + a]      * rwin[d / 3][p + d % 3];
                    acc += w_sw2[d * 20 + 10 + a] * vwin[d / 3][p + d % 3];
                }
                qv[p][a] = acc;
            }
        }
        // store q: out[2048 + ((b*64+row)*64 + xx)*10 + a]
        #pragma unroll
        for (int p = 0; p < 4; ++p) {
            float* qp = out + 2048 + ((size_t)((b * 64 + row) * 64 + cb + p)) * 10;
            #pragma unroll
            for (int h2 = 0; h2 < 5; ++h2)
                ((float2*)qp)[h2] = make_float2(qv[p][h2 * 2], qv[p][h2 * 2 + 1]);
        }
        #pragma unroll
        for (int p = 0; p < 4; ++p)
            if (row == s1 && s2 == cb + p) {
                #pragma unroll
                for (int a = 0; a < 10; ++a) qsel[a] = qv[p][a];
            }
    }
    __syncthreads();

    // ---- dense + softmax (thread 0), q_out (threads 0..9) ----
    if (t == 0) {
        float logits[8];
        float m = -1e30f;
        #pragma unroll
        for (int j = 0; j < 8; ++j) {
            float s = 0.f;
            #pragma unroll
            for (int a = 0; a < 10; ++a) s += qsel[a] * w_dense[a * 8 + j];
            logits[j] = s;
            m = fmaxf(m, s);
        }
        float sum = 0.f;
        float e[8];
        #pragma unroll
        for (int j = 0; j < 8; ++j) { e[j] = expf(logits[j] - m); sum += e[j]; }
        float inv = 1.f / sum;
        #pragma unroll
        for (int j = 0; j < 8; ++j) {
            out[b * 8 + j] = logits[j];
            out[1024 + b * 8 + j] = e[j] * inv;
        }
    }
    if (t < 10) out[5244928 + b * 10 + t] = qsel[t];
}

extern "C" void kernel_launch(void* const* d_in, const int* in_sizes, int n_in,
                              void* d_out, int out_size, void* d_ws, size_t ws_size,
                              hipStream_t stream) {
    const float* x      = (const float*)d_in[0];
    const int*   S1     = (const int*)d_in[1];
    const int*   S2     = (const int*)d_in[2];
    const int*   VInum  = (const int*)d_in[3];
    const float* w0     = (const float*)d_in[4];
    const float* b0     = (const float*)d_in[5];
    const float* w_r    = (const float*)d_in[6];
    const float* w_q    = (const float*)d_in[7];
    const float* w_sw   = (const float*)d_in[8];
    const float* w_sw2  = (const float*)d_in[9];
    const float* w_dense= (const float*)d_in[10];
    float* out = (float*)d_out;
    float* ws  = (float*)d_ws;

    prep_kernel<<<1, 64, 0, stream>>>(w0, b0, w_r, ws);
    vin_kernel<<<128, 1024, 0, stream>>>(x, S1, S2, VInum, w0, w_r, w_q, w_sw,
                                         w_sw2, w_dense, ws, out);
}